// Round 1
// baseline (236.216 us; speedup 1.0000x reference)
//
#include <hip/hip_runtime.h>

// Problem: B=4, T=4096, C=512, H=64 single attention head, causal, scale=C^-0.5.
// Inputs fp32: x[4,4096,512], Wk/Wq/Wv[512,64]. Output fp32 [4,4096,64].
// Strategy: bf16 MFMA for both GEMM stages (2% absmax budget allows bf16).

typedef __attribute__((ext_vector_type(8))) __bf16 bf16x8;
typedef __attribute__((ext_vector_type(4))) float f32x4;

#define B_ 4
#define T_ 4096
#define C_ 512
#define H_ 64
#define BT (B_ * T_)

__device__ __forceinline__ unsigned short f2bf(float f) {
    unsigned int u = __builtin_bit_cast(unsigned int, f);
    u += 0x7fffu + ((u >> 16) & 1u);   // round-to-nearest-even
    return (unsigned short)(u >> 16);
}

__device__ __forceinline__ f32x4 mfma16(bf16x8 a, bf16x8 b, f32x4 c) {
    return __builtin_amdgcn_mfma_f32_16x16x32_bf16(a, b, c, 0, 0, 0);
}

__device__ __forceinline__ bf16x8 lds_frag(const unsigned short* p) {
    return *(const bf16x8*)p;
}

// ---------------------------------------------------------------------------
// Kernel 0: Wt[m][h][c] = bf16(W_m[c][h]), m in {0:k, 1:q, 2:v}
// ---------------------------------------------------------------------------
__global__ __launch_bounds__(256) void wt_kernel(const float* __restrict__ Wk,
                                                 const float* __restrict__ Wq,
                                                 const float* __restrict__ Wv,
                                                 unsigned short* __restrict__ Wt) {
    int gid = blockIdx.x * 256 + threadIdx.x;          // 3*64*512 = 98304 threads
    int m = gid >> 15;
    int rem = gid & 32767;
    int h = rem >> 9;
    int c = rem & 511;
    const float* W = (m == 0) ? Wk : ((m == 1) ? Wq : Wv);
    Wt[gid] = f2bf(W[c * H_ + h]);
}

// ---------------------------------------------------------------------------
// Kernel 1: q/k/v projections.  One block = 64 t-rows, 4 waves (16-row strips).
// x staged fp32->bf16 in LDS (pitch 520 bf16 => 2-way bank aliasing, free).
// B-fragments read straight from global Wt (L2-resident, 192 KB total).
// ---------------------------------------------------------------------------
#define XP 520  // LDS pitch in bf16 elements

__global__ __launch_bounds__(256) void proj_kernel(const float* __restrict__ x,
                                                   const unsigned short* __restrict__ Wt,
                                                   unsigned short* __restrict__ k_ws,
                                                   unsigned short* __restrict__ q_ws,
                                                   unsigned short* __restrict__ v_ws) {
    __shared__ unsigned short Xs[64 * XP];
    const int tid = threadIdx.x;
    const int t0 = blockIdx.x * 64;

    // Stage x tile [64][512] fp32 -> bf16 LDS, coalesced float4 reads.
    for (int i = 0; i < 32; ++i) {
        int e4 = tid + i * 256;                 // 8192 float4 total
        int row = e4 >> 7;                      // 128 float4 per row
        int c4 = (e4 & 127) << 2;
        const float4 xv = ((const float4*)x)[(long)(t0 + row) * 128 + (e4 & 127)];
        unsigned int lo = (unsigned int)f2bf(xv.x) | ((unsigned int)f2bf(xv.y) << 16);
        unsigned int hi = (unsigned int)f2bf(xv.z) | ((unsigned int)f2bf(xv.w) << 16);
        unsigned int* p = (unsigned int*)&Xs[row * XP + c4];
        p[0] = lo;
        p[1] = hi;
    }
    __syncthreads();

    const int wave = tid >> 6;
    const int lane = tid & 63;
    const int lane15 = lane & 15;
    const int quad = lane >> 4;
    const int rowA = wave * 16 + lane15;

    f32x4 acc[12];  // [m3*4 + nt]
    for (int i = 0; i < 12; ++i) acc[i] = (f32x4){0.f, 0.f, 0.f, 0.f};

    for (int kc = 0; kc < 16; ++kc) {
        bf16x8 a = lds_frag(&Xs[rowA * XP + kc * 32 + quad * 8]);
#pragma unroll
        for (int m3 = 0; m3 < 3; ++m3) {
#pragma unroll
            for (int nt = 0; nt < 4; ++nt) {
                const bf16x8 b = *(const bf16x8*)&Wt[((m3 * 64 + nt * 16 + lane15) * C_) + kc * 32 + quad * 8];
                acc[m3 * 4 + nt] = mfma16(a, b, acc[m3 * 4 + nt]);
            }
        }
    }

    unsigned short* outs[3] = {k_ws, q_ws, v_ws};
#pragma unroll
    for (int m3 = 0; m3 < 3; ++m3) {
#pragma unroll
        for (int nt = 0; nt < 4; ++nt) {
#pragma unroll
            for (int r = 0; r < 4; ++r) {
                int row = t0 + wave * 16 + quad * 4 + r;   // C layout: row=(lane>>4)*4+r
                int col = nt * 16 + lane15;                // col=lane&15
                outs[m3][row * H_ + col] = f2bf(acc[m3 * 4 + nt][r]);
            }
        }
    }
}

// ---------------------------------------------------------------------------
// Kernel 2: flash attention.  Block = (b, 64-row Q tile), 4 waves x 16-row strips.
// ---------------------------------------------------------------------------
#define AP 72  // LDS pitch bf16 (2-way bank aliasing on b128 frag reads: free)

__global__ __launch_bounds__(256) void attn_kernel(const unsigned short* __restrict__ q_ws,
                                                   const unsigned short* __restrict__ k_ws,
                                                   const unsigned short* __restrict__ v_ws,
                                                   float* __restrict__ out) {
    __shared__ unsigned short Qs[64 * AP];
    __shared__ unsigned short Ks[64 * AP];
    __shared__ unsigned short Vt[64 * AP];  // [h][s]
    __shared__ unsigned short Ps[64 * AP];

    const int tid = threadIdx.x;
    const int q0 = blockIdx.x * 64;
    const int base = blockIdx.y * T_;
    const int wave = tid >> 6;
    const int lane = tid & 63;
    const int lane15 = lane & 15;
    const int quad = lane >> 4;

    // Stage Q tile (bf16, coalesced 4B loads).
    for (int i = 0; i < 8; ++i) {
        int e2 = tid + i * 256;               // 2048 uints
        int s = e2 >> 5, h2 = e2 & 31;
        unsigned int val = ((const unsigned int*)q_ws)[(long)(base + q0 + s) * 32 + h2];
        *(unsigned int*)&Qs[s * AP + h2 * 2] = val;
    }
    __syncthreads();

    bf16x8 qf[2];
    qf[0] = lds_frag(&Qs[(wave * 16 + lane15) * AP + 0 * 32 + quad * 8]);
    qf[1] = lds_frag(&Qs[(wave * 16 + lane15) * AP + 1 * 32 + quad * 8]);

    float m_r[4], l_r[4];
    f32x4 o_acc[4];
#pragma unroll
    for (int r = 0; r < 4; ++r) { m_r[r] = -__builtin_inff(); l_r[r] = 0.f; }
#pragma unroll
    for (int hf = 0; hf < 4; ++hf) o_acc[hf] = (f32x4){0.f, 0.f, 0.f, 0.f};

    const float scale = 0.04419417382415922f;  // 512^-0.5

    for (int s0 = 0; s0 <= q0; s0 += 64) {
        __syncthreads();  // all waves done reading previous Ks/Vt
        // Stage K row-major and V transposed.
        for (int i = 0; i < 8; ++i) {
            int e2 = tid + i * 256;
            int s = e2 >> 5, h2 = e2 & 31;
            unsigned int kv = ((const unsigned int*)k_ws)[(long)(base + s0 + s) * 32 + h2];
            *(unsigned int*)&Ks[s * AP + h2 * 2] = kv;
            unsigned int vv = ((const unsigned int*)v_ws)[(long)(base + s0 + s) * 32 + h2];
            Vt[(h2 * 2 + 0) * AP + s] = (unsigned short)(vv & 0xffffu);
            Vt[(h2 * 2 + 1) * AP + s] = (unsigned short)(vv >> 16);
        }
        __syncthreads();

        // S = Q K^T  (wave strip: rows 16w..16w+15, cols 0..63)
        f32x4 sf[4];
#pragma unroll
        for (int ct = 0; ct < 4; ++ct) {
            bf16x8 k0 = lds_frag(&Ks[(ct * 16 + lane15) * AP + 0 * 32 + quad * 8]);
            bf16x8 k1 = lds_frag(&Ks[(ct * 16 + lane15) * AP + 1 * 32 + quad * 8]);
            f32x4 z = (f32x4){0.f, 0.f, 0.f, 0.f};
            z = mfma16(qf[0], k0, z);
            z = mfma16(qf[1], k1, z);
            sf[ct] = z;
        }

        // scale + causal mask (only the diagonal tile needs masking)
#pragma unroll
        for (int ct = 0; ct < 4; ++ct)
#pragma unroll
            for (int r = 0; r < 4; ++r) sf[ct][r] *= scale;
        if (s0 == q0) {
#pragma unroll
            for (int ct = 0; ct < 4; ++ct) {
                int col = ct * 16 + lane15;
#pragma unroll
                for (int r = 0; r < 4; ++r) {
                    int row = wave * 16 + quad * 4 + r;
                    if (col > row) sf[ct][r] = -3.0e38f;
                }
            }
        }

        // Online softmax: row r lives in 16 contiguous lanes (quad group).
#pragma unroll
        for (int r = 0; r < 4; ++r) {
            float mx = fmaxf(fmaxf(sf[0][r], sf[1][r]), fmaxf(sf[2][r], sf[3][r]));
            mx = fmaxf(mx, __shfl_xor(mx, 1));
            mx = fmaxf(mx, __shfl_xor(mx, 2));
            mx = fmaxf(mx, __shfl_xor(mx, 4));
            mx = fmaxf(mx, __shfl_xor(mx, 8));
            float mnew = fmaxf(m_r[r], mx);
            float alpha = __expf(m_r[r] - mnew);   // first tile: exp(-inf)=0
            float rs = 0.f;
#pragma unroll
            for (int ct = 0; ct < 4; ++ct) {
                float p = __expf(sf[ct][r] - mnew);
                sf[ct][r] = p;
                rs += p;
            }
            rs += __shfl_xor(rs, 1);
            rs += __shfl_xor(rs, 2);
            rs += __shfl_xor(rs, 4);
            rs += __shfl_xor(rs, 8);
            l_r[r] = l_r[r] * alpha + rs;
            m_r[r] = mnew;
            o_acc[0][r] *= alpha;
            o_acc[1][r] *= alpha;
            o_acc[2][r] *= alpha;
            o_acc[3][r] *= alpha;
        }

        // P (C layout) -> LDS bf16 -> re-read in A layout.
#pragma unroll
        for (int ct = 0; ct < 4; ++ct)
#pragma unroll
            for (int r = 0; r < 4; ++r)
                Ps[(wave * 16 + quad * 4 + r) * AP + ct * 16 + lane15] = f2bf(sf[ct][r]);
        __syncthreads();  // also fences compiler reordering of LDS ops

        bf16x8 pa0 = lds_frag(&Ps[(wave * 16 + lane15) * AP + 0 * 32 + quad * 8]);
        bf16x8 pa1 = lds_frag(&Ps[(wave * 16 + lane15) * AP + 1 * 32 + quad * 8]);
#pragma unroll
        for (int hf = 0; hf < 4; ++hf) {
            bf16x8 v0 = lds_frag(&Vt[(hf * 16 + lane15) * AP + 0 * 32 + quad * 8]);
            bf16x8 v1 = lds_frag(&Vt[(hf * 16 + lane15) * AP + 1 * 32 + quad * 8]);
            o_acc[hf] = mfma16(pa0, v0, o_acc[hf]);
            o_acc[hf] = mfma16(pa1, v1, o_acc[hf]);
        }
    }

    // Epilogue: out = O / l
#pragma unroll
    for (int hf = 0; hf < 4; ++hf) {
#pragma unroll
        for (int r = 0; r < 4; ++r) {
            int row = q0 + wave * 16 + quad * 4 + r;
            out[(long)(base + row) * H_ + hf * 16 + lane15] = o_acc[hf][r] / l_r[r];
        }
    }
}

// ---------------------------------------------------------------------------
extern "C" void kernel_launch(void* const* d_in, const int* in_sizes, int n_in,
                              void* d_out, int out_size, void* d_ws, size_t ws_size,
                              hipStream_t stream) {
    const float* x  = (const float*)d_in[0];
    const float* Wk = (const float*)d_in[1];
    const float* Wq = (const float*)d_in[2];
    const float* Wv = (const float*)d_in[3];
    float* out = (float*)d_out;

    char* ws = (char*)d_ws;
    unsigned short* k_ws = (unsigned short*)(ws);                       // 2 MB
    unsigned short* q_ws = (unsigned short*)(ws + (2u << 20));          // 2 MB
    unsigned short* v_ws = (unsigned short*)(ws + (4u << 20));          // 2 MB
    unsigned short* Wt   = (unsigned short*)(ws + (6u << 20));          // 192 KB

    wt_kernel<<<384, 256, 0, stream>>>(Wk, Wq, Wv, Wt);
    proj_kernel<<<BT / 64, 256, 0, stream>>>(x, Wt, k_ws, q_ws, v_ws);
    attn_kernel<<<dim3(T_ / 64, B_), 256, 0, stream>>>(q_ws, k_ws, v_ws, out);
}